// Round 7
// baseline (1683.629 us; speedup 1.0000x reference)
//
#include <hip/hip_runtime.h>
#include <hip/hip_bf16.h>

#define B_   32
#define T_   128
#define H_   700
#define HP2  768          // h K-pad: 4 waves x 6 k-tiles x 32
#define E_   100
#define G3   2100
#define V_   32000
#define DY_  200
#define DZ_  500
#define KP   704          // g / Wb K-pad for projection GEMM
#define NBLK 44
#define JW   16           // hidden cols per block; 3 gates -> 3 n-tiles of 16
#define FSTR 16
#define BT   4096

typedef __attribute__((ext_vector_type(8))) short bf16x8;
typedef __attribute__((ext_vector_type(4))) float f32x4;

__device__ __forceinline__ unsigned ld_flag(const unsigned* p) {
    return __hip_atomic_load(p, __ATOMIC_RELAXED, __HIP_MEMORY_SCOPE_AGENT);
}
__device__ __forceinline__ void st_flag(unsigned* p, unsigned v) {
    __hip_atomic_store(p, v, __ATOMIC_RELAXED, __HIP_MEMORY_SCOPE_AGENT);
}
__device__ __forceinline__ unsigned long long ld_h8(const unsigned long long* p) {
    return __hip_atomic_load(p, __ATOMIC_RELAXED, __HIP_MEMORY_SCOPE_AGENT);
}
__device__ __forceinline__ void st_h8(unsigned long long* p, unsigned long long v) {
    __hip_atomic_store(p, v, __ATOMIC_RELAXED, __HIP_MEMORY_SCOPE_AGENT);
}
// split fp32 into bf16 hi + bf16 lo (residual)
__device__ __forceinline__ void split_bf(float v, short& hi, short& lo) {
    __hip_bfloat16 h = __float2bfloat16(v);
    float r = v - __bfloat162float(h);
    __hip_bfloat16 l = __float2bfloat16(r);
    hi = *reinterpret_cast<short*>(&h);
    lo = *reinterpret_cast<short*>(&l);
}

// ---------------- proj_W [700][32000] fp32 -> Wb [32000][704] bf16 ----------------
__global__ __launch_bounds__(256)
void wconv_kernel(const float* __restrict__ W, __hip_bfloat16* __restrict__ Wb) {
    __shared__ float tile[32][33];
    const int n0 = blockIdx.x * 32, k0 = blockIdx.y * 32;
    const int tx = threadIdx.x, ty = threadIdx.y;
    #pragma unroll
    for (int i = 0; i < 4; ++i) {
        int k = k0 + ty + 8 * i;
        float v = (k < H_) ? W[(size_t)k * V_ + n0 + tx] : 0.0f;
        tile[ty + 8 * i][tx] = v;
    }
    __syncthreads();
    #pragma unroll
    for (int i = 0; i < 4; ++i) {
        int nn = ty + 8 * i;
        Wb[(size_t)(n0 + nn) * KP + k0 + tx] = __float2bfloat16(tile[tx][nn]);
    }
}

// ---------------- xp[b*T+t][2100] = emb[dec[b][t]] @ gru1_k + gru1_b[0]; zero g pads ----------------
__global__ __launch_bounds__(256)
void xp_kernel(const int* __restrict__ di, const float* __restrict__ emb,
               const float* __restrict__ gk, const float* __restrict__ gb,
               float* __restrict__ xp, __hip_bfloat16* __restrict__ g_out) {
    __shared__ float xl[E_];
    const int row = blockIdx.x;
    const int tid = threadIdx.x;
    if (tid < E_) xl[tid] = emb[(size_t)di[row] * E_ + tid];
    if (tid < KP - H_) g_out[(size_t)row * KP + H_ + tid] = __float2bfloat16(0.0f);
    __syncthreads();
    for (int j4 = tid; j4 < G3 / 4; j4 += 256) {
        int j = j4 * 4;
        float4 a = *(const float4*)&gb[j];
        #pragma unroll 4
        for (int k = 0; k < E_; ++k) {
            float xv = xl[k];
            float4 wv = *(const float4*)&gk[(size_t)k * G3 + j];
            a.x += xv * wv.x; a.y += xv * wv.y; a.z += xv * wv.z; a.w += xv * wv.w;
        }
        *(float4*)&xp[(size_t)row * G3 + j] = a;
    }
}

// ---------------- xp[bt][c] -> xp_t[c][t*32+b] ----------------
__global__ __launch_bounds__(256)
void xpt_kernel(const float* __restrict__ xp, float* __restrict__ xpt) {
    __shared__ float tl[32][33];
    const int c0 = blockIdx.x * 32, t = blockIdx.y;
    const int tx = threadIdx.x, ty = threadIdx.y;
    #pragma unroll
    for (int i = 0; i < 4; ++i) {
        int b = ty + 8 * i, c = c0 + tx;
        tl[b][tx] = (c < G3) ? xp[(size_t)(b * T_ + t) * G3 + c] : 0.0f;
    }
    __syncthreads();
    #pragma unroll
    for (int i = 0; i < 4; ++i) {
        int cc = ty + 8 * i;
        if (c0 + cc < G3)
            xpt[(size_t)(c0 + cc) * BT + t * 32 + tx] = tl[tx][cc];
    }
}

// ---------------- mask[b][t][j] -> mask_t[j][t*32+b] (bf16; mask in {0,2} exact) ----------------
__global__ __launch_bounds__(256)
void maskt_kernel(const float* __restrict__ mask, __hip_bfloat16* __restrict__ mkt) {
    __shared__ float tl[32][33];
    const int j0 = blockIdx.x * 32, t = blockIdx.y;
    const int tx = threadIdx.x, ty = threadIdx.y;
    #pragma unroll
    for (int i = 0; i < 4; ++i) {
        int b = ty + 8 * i, j = j0 + tx;
        tl[b][tx] = (j < H_) ? mask[(size_t)(b * T_ + t) * H_ + j] : 0.0f;
    }
    __syncthreads();
    #pragma unroll
    for (int i = 0; i < 4; ++i) {
        int cc = ty + 8 * i;
        if (j0 + cc < H_)
            mkt[(size_t)(j0 + cc) * BT + t * 32 + tx] = __float2bfloat16(tl[tx][cc]);
    }
}

// ---------------- persistent GRU: 44 blocks, MFMA hi/lo, pre-split h planes ----------------
// Block owns JW=16 hidden cols -> one 16-wide n-tile PER GATE (3 n-tiles).
// 4 waves each own K-range 192 (6 k-tiles of 32). rk B-frags in registers (hi/lo bf16).
// h exchanged as hi/lo bf16 planes via device-scope (sc1) loads/stores;
// per-block monotonic flags. Placement-independent: no XCD assumptions.
__global__ __launch_bounds__(256, 1)
void gru_kernel(const float* __restrict__ labels, const float* __restrict__ zin,
                const float* __restrict__ W1, const float* __restrict__ b1,
                const float* __restrict__ xpt, const __hip_bfloat16* __restrict__ mkt,
                const float* __restrict__ rk, const float* __restrict__ gb,
                unsigned short* __restrict__ hhi, unsigned short* __restrict__ hlo,
                __hip_bfloat16* __restrict__ g_out, unsigned* __restrict__ flags) {
    __shared__ float part2[4 * 2 * 16 * 49];      // [wv][m][row][3*16+pad] = 25088 B
    __shared__ float xbuf[48 * 32];               // [gI*16+jl][b]
    __shared__ float mbuf[16 * 32];               // [jl][b]
    __shared__ alignas(8) short smhi[32 * 16], smlo[32 * 16];   // [b][jl]

    const int tid = threadIdx.x;
    const int blk = blockIdx.x;
    const int j0  = blk * JW;
    const int wv = tid >> 6, lane = tid & 63, lr = lane & 15, lkg = lane >> 4;

    // ---- rk B-frags in registers (hi/lo). tile n = gate n; col j = j0+lr ----
    bf16x8 bhi[3][6], blo[3][6];
    {
        const int j = j0 + lr;
        #pragma unroll
        for (int n = 0; n < 3; ++n)
            #pragma unroll
            for (int t = 0; t < 6; ++t) {
                bf16x8 h8, l8;
                #pragma unroll
                for (int i = 0; i < 8; ++i) {
                    int k = wv * 192 + t * 32 + lkg * 8 + i;
                    float v = (j < H_ && k < H_) ? rk[(size_t)k * G3 + n * H_ + j] : 0.0f;
                    short hi, lo; split_bf(v, hi, lo);
                    h8[i] = hi; l8[i] = lo;
                }
                bhi[n][t] = h8; blo[n][t] = l8;
            }
    }

    // ---- h0 + step-invariant biases (2 outputs per thread) ----
    float hold[2], bzv[2], brv[2], bhv[2];
    #pragma unroll
    for (int oo = 0; oo < 2; ++oo) {
        int o = tid + oo * 256;
        int b = o & 31, jl = o >> 5, j = j0 + jl;
        float v = 0.f; bzv[oo] = 0.f; brv[oo] = 0.f; bhv[oo] = 0.f;
        if (j < H_) {
            bzv[oo] = gb[G3 + j];
            brv[oo] = gb[G3 + H_ + j];
            bhv[oo] = gb[G3 + 2 * H_ + j];
            v = (j < DY_) ? labels[b] * W1[j] + b1[j] : zin[b * DZ_ + (j - DY_)];
        }
        hold[oo] = v;
        short hi, lo; split_bf(v, hi, lo);
        smhi[b * 16 + jl] = hi; smlo[b * 16 + jl] = lo;
    }
    // ---- zero static K-pads [704,768) once (block 0), both parities/planes ----
    if (blk == 0) {
        for (int e = tid; e < 2048; e += 256) {
            int pl = e >> 10, par = (e >> 9) & 1, row = (e >> 4) & 31, q = e & 15;
            unsigned short* base = (pl ? hlo : hhi) + (size_t)par * 24576 + row * 768 + 704;
            st_h8((unsigned long long*)base + q, 0ull);
        }
    }
    __syncthreads();
    // publish h0 (parity 0): 2 planes x 32 rows x 4 u64 = 256 stores
    {
        int pl = tid >> 7, r64 = tid & 127, row = r64 >> 2, q = r64 & 3;
        const unsigned long long* src = (const unsigned long long*)(pl ? smlo : smhi);
        unsigned short* dst = (pl ? hlo : hhi) + (size_t)row * 768 + j0;
        st_h8((unsigned long long*)dst + q, src[row * 4 + q]);
    }
    __syncthreads();                       // drains vmcnt: stores complete
    if (tid == 0) st_flag(&flags[blk * FSTR], 1u);

    const int i0 = lr * 192 + wv * 48 + lkg * 2;   // u64 index: row lr
    const int i1 = i0 + 16 * 192;                  // row 16+lr

    struct Chunk { unsigned long long d[8]; };
    union FragU { unsigned long long d[2]; bf16x8 v; };

    for (int step = 0; step < T_; ++step) {
        const int cur = step & 1, nxt = cur ^ 1;
        const unsigned long long* phz = (const unsigned long long*)(hhi + (size_t)cur * 24576);
        const unsigned long long* plz = (const unsigned long long*)(hlo + (size_t)cur * 24576);

        // phase 1: prefetch x/mask (cached loads; overlap the poll)
        for (int e = tid; e < 1536; e += 256) {
            int run = e >> 5, b = e & 31;
            int gI = run >> 4, jl = run & 15, j = j0 + jl;
            xbuf[e] = (j < H_) ? xpt[(size_t)(gI * H_ + j) * BT + step * 32 + b] : 0.f;
        }
        for (int e = tid; e < 512; e += 256) {
            int jl = e >> 5, b = e & 31, j = j0 + jl;
            mbuf[e] = (j < H_) ? __bfloat162float(mkt[(size_t)j * BT + step * 32 + b]) : 0.f;
        }
        // phase 2: wait for all 44 blocks' h_step
        if (tid < NBLK) {
            while (ld_flag(&flags[tid * FSTR]) < (unsigned)(step + 1))
                __builtin_amdgcn_s_sleep(1);
        }
        __syncthreads();

        // phase 3+4: 3-deep pipelined pull + MFMA (static indices)
        f32x4 acc[2][3];
        #pragma unroll
        for (int m = 0; m < 2; ++m)
            #pragma unroll
            for (int n = 0; n < 3; ++n) acc[m][n] = (f32x4){0.f, 0.f, 0.f, 0.f};
        Chunk c0, c1, c2;

#define LOADC(T, C) do { \
        (C).d[0] = ld_h8(phz + i0 + (T) * 8); \
        (C).d[1] = ld_h8(phz + i0 + (T) * 8 + 1); \
        (C).d[2] = ld_h8(plz + i0 + (T) * 8); \
        (C).d[3] = ld_h8(plz + i0 + (T) * 8 + 1); \
        (C).d[4] = ld_h8(phz + i1 + (T) * 8); \
        (C).d[5] = ld_h8(phz + i1 + (T) * 8 + 1); \
        (C).d[6] = ld_h8(plz + i1 + (T) * 8); \
        (C).d[7] = ld_h8(plz + i1 + (T) * 8 + 1); \
    } while (0)
#define PROCC(T, C) do { \
        FragU fh0, fl0, fh1, fl1; \
        fh0.d[0] = (C).d[0]; fh0.d[1] = (C).d[1]; \
        fl0.d[0] = (C).d[2]; fl0.d[1] = (C).d[3]; \
        fh1.d[0] = (C).d[4]; fh1.d[1] = (C).d[5]; \
        fl1.d[0] = (C).d[6]; fl1.d[1] = (C).d[7]; \
        _Pragma("unroll") \
        for (int n = 0; n < 3; ++n) { \
            acc[0][n] = __builtin_amdgcn_mfma_f32_16x16x32_bf16(fh0.v, bhi[n][T], acc[0][n], 0, 0, 0); \
            acc[0][n] = __builtin_amdgcn_mfma_f32_16x16x32_bf16(fh0.v, blo[n][T], acc[0][n], 0, 0, 0); \
            acc[0][n] = __builtin_amdgcn_mfma_f32_16x16x32_bf16(fl0.v, bhi[n][T], acc[0][n], 0, 0, 0); \
            acc[1][n] = __builtin_amdgcn_mfma_f32_16x16x32_bf16(fh1.v, bhi[n][T], acc[1][n], 0, 0, 0); \
            acc[1][n] = __builtin_amdgcn_mfma_f32_16x16x32_bf16(fh1.v, blo[n][T], acc[1][n], 0, 0, 0); \
            acc[1][n] = __builtin_amdgcn_mfma_f32_16x16x32_bf16(fl1.v, bhi[n][T], acc[1][n], 0, 0, 0); \
        } \
    } while (0)

        LOADC(0, c0); LOADC(1, c1);
        LOADC(2, c2); PROCC(0, c0);
        LOADC(3, c0); PROCC(1, c1);
        LOADC(4, c1); PROCC(2, c2);
        LOADC(5, c2); PROCC(3, c0);
        PROCC(4, c1); PROCC(5, c2);
#undef LOADC
#undef PROCC

        // phase 5: per-wave partials (C: col=lane&15, row=lkg*4+reg)
        #pragma unroll
        for (int m = 0; m < 2; ++m)
            #pragma unroll
            for (int n = 0; n < 3; ++n)
                #pragma unroll
                for (int r4 = 0; r4 < 4; ++r4)
                    part2[((wv * 2 + m) * 16 + lkg * 4 + r4) * 49 + n * 16 + lr] = acc[m][n][r4];
        __syncthreads();

        // phase 6: gates (512 outputs = 2 per thread)
        #pragma unroll
        for (int oo = 0; oo < 2; ++oo) {
            int o = tid + oo * 256;
            int b = o & 31, jl = o >> 5, j = j0 + jl;
            int m = b >> 4, row = b & 15;
            float hn = 0.f;
            if (j < H_) {
                float hp0 = bzv[oo], hp1 = brv[oo], hp2 = bhv[oo];
                #pragma unroll
                for (int w = 0; w < 4; ++w) {
                    int base = ((w * 2 + m) * 16 + row) * 49;
                    hp0 += part2[base + jl];
                    hp1 += part2[base + 16 + jl];
                    hp2 += part2[base + 32 + jl];
                }
                float xz = xbuf[(0 * 16 + jl) * 32 + b];
                float xr = xbuf[(1 * 16 + jl) * 32 + b];
                float xh = xbuf[(2 * 16 + jl) * 32 + b];
                float mv = mbuf[jl * 32 + b];
                float zg = 1.0f / (1.0f + expf(-(xz + hp0)));
                float rg = 1.0f / (1.0f + expf(-(xr + hp1)));
                float hh = tanhf(xh + rg * hp2);
                hn = zg * hold[oo] + (1.0f - zg) * hh;
                g_out[(size_t)(b * T_ + step) * KP + j] = __float2bfloat16(hn * mv);
            }
            hold[oo] = hn;
            short hi, lo; split_bf(hn, hi, lo);
            smhi[b * 16 + jl] = hi; smlo[b * 16 + jl] = lo;
        }
        __syncthreads();
        // publish h_{step+1} (parity nxt)
        {
            int pl = tid >> 7, r64 = tid & 127, row = r64 >> 2, q = r64 & 3;
            const unsigned long long* src = (const unsigned long long*)(pl ? smlo : smhi);
            unsigned short* dst = (pl ? hlo : hhi) + (size_t)nxt * 24576 + (size_t)row * 768 + j0;
            st_h8((unsigned long long*)dst + q, src[row * 4 + q]);
        }
        __syncthreads();                   // drains vmcnt: stores complete
        if (tid == 0) st_flag(&flags[blk * FSTR], (unsigned)(step + 2));
    }
}

// ---------------- projection GEMM: C[4096][32000] = g @ Wb^T + bias ----------------
__global__ __launch_bounds__(256)
void gemm_kernel(const __hip_bfloat16* __restrict__ A, const __hip_bfloat16* __restrict__ Bw,
                 const float* __restrict__ bias, float* __restrict__ C) {
    __shared__ alignas(16) unsigned short As[128][72];
    __shared__ alignas(16) unsigned short Bs[128][72];
    const int tid = threadIdx.x;
    const int bid = blockIdx.x;
    const int co = (bid & 7) * 1000 + (bid >> 3);   // bijective XCD-chunked swizzle
    const int bm = co & 31, bn = co >> 5;
    const int rowbase = bm * 128, colbase = bn * 128;
    const int lane = tid & 63, w = tid >> 6;
    const int wm = w >> 1, wn = w & 1;
    const int lr = lane & 15, lkg = lane >> 4;

    f32x4 acc[4][4];
    #pragma unroll
    for (int i = 0; i < 4; ++i)
        #pragma unroll
        for (int j = 0; j < 4; ++j) acc[i][j] = (f32x4){0.f, 0.f, 0.f, 0.f};

    const int srow = tid >> 3, skk = (tid & 7) * 8;

    for (int kt = 0; kt < 11; ++kt) {
        const int k0 = kt * 64;
        __syncthreads();
        #pragma unroll
        for (int i = 0; i < 4; ++i) {
            int r = srow + i * 32;
            *(uint4*)&As[r][skk] = *(const uint4*)&A[(size_t)(rowbase + r) * KP + k0 + skk];
            *(uint4*)&Bs[r][skk] = *(const uint4*)&Bw[(size_t)(colbase + r) * KP + k0 + skk];
        }
        __syncthreads();
        #pragma unroll
        for (int ks = 0; ks < 2; ++ks) {
            bf16x8 af[4], bf[4];
            #pragma unroll
            for (int i = 0; i < 4; ++i)
                af[i] = *(const bf16x8*)&As[wm * 64 + i * 16 + lr][ks * 32 + lkg * 8];
            #pragma unroll
            for (int j = 0; j < 4; ++j)
                bf[j] = *(const bf16x8*)&Bs[wn * 64 + j * 16 + lr][ks * 32 + lkg * 8];
            #pragma unroll
            for (int i = 0; i < 4; ++i)
                #pragma unroll
                for (int j = 0; j < 4; ++j)
                    acc[i][j] = __builtin_amdgcn_mfma_f32_16x16x32_bf16(af[i], bf[j], acc[i][j], 0, 0, 0);
        }
    }

    float bv[4];
    #pragma unroll
    for (int j = 0; j < 4; ++j) bv[j] = bias[colbase + wn * 64 + j * 16 + lr];
    #pragma unroll
    for (int i = 0; i < 4; ++i) {
        int grow0 = rowbase + wm * 64 + i * 16 + lkg * 4;
        #pragma unroll
        for (int j = 0; j < 4; ++j) {
            int gcol = colbase + wn * 64 + j * 16 + lr;
            #pragma unroll
            for (int r = 0; r < 4; ++r)
                C[(size_t)(grow0 + r) * V_ + gcol] = acc[i][j][r] + bv[j];
        }
    }
}

extern "C" void kernel_launch(void* const* d_in, const int* in_sizes, int n_in,
                              void* d_out, int out_size, void* d_ws, size_t ws_size,
                              hipStream_t stream) {
    const float* labels = (const float*)d_in[0];
    const float* z      = (const float*)d_in[1];
    const int*   di     = (const int*)d_in[2];
    const float* mask   = (const float*)d_in[3];
    const float* emb    = (const float*)d_in[4];
    const float* W1     = (const float*)d_in[5];
    const float* b1     = (const float*)d_in[6];
    const float* g1k    = (const float*)d_in[7];
    const float* g1rk   = (const float*)d_in[8];
    const float* g1b    = (const float*)d_in[9];
    const float* pW     = (const float*)d_in[10];
    const float* pb     = (const float*)d_in[11];

    // ws: long-lived buffers (~51 MB)
    char* ws = (char*)d_ws;
    __hip_bfloat16* g    = (__hip_bfloat16*)ws;                    //  5,767,168 B
    __hip_bfloat16* Wb   = (__hip_bfloat16*)(ws + 5767168);        // 45,056,000 B
    unsigned short* hhi  = (unsigned short*)(ws + 50823168);       //     98,304 B
    unsigned short* hlo  = (unsigned short*)(ws + 50921472);       //     98,304 B
    unsigned*       flags= (unsigned*)(ws + 51019776);             //      2,816 B

    // d_out doubles as scratch for GRU-phase-only data (dead before gemm writes C)
    char* ob = (char*)d_out;
    float*          xpt  = (float*)ob;                             // 34,406,400 B
    __hip_bfloat16* mkt  = (__hip_bfloat16*)(ob + 34406400);       //  5,734,400 B
    float*          xp   = (float*)(ob + 40140800);                // 34,406,400 B

    hipMemsetAsync(flags, 0, NBLK * FSTR * sizeof(unsigned), stream);

    wconv_kernel<<<dim3(1000, 22), dim3(32, 8), 0, stream>>>(pW, Wb);
    xp_kernel<<<dim3(4096), 256, 0, stream>>>(di, emb, g1k, g1b, xp, g);
    xpt_kernel<<<dim3(66, 128), dim3(32, 8), 0, stream>>>(xp, xpt);
    maskt_kernel<<<dim3(22, 128), dim3(32, 8), 0, stream>>>(mask, mkt);

    gru_kernel<<<dim3(NBLK), 256, 0, stream>>>(labels, z, W1, b1, xpt, mkt,
                                               g1rk, g1b, hhi, hlo, g, flags);

    gemm_kernel<<<dim3(8000), 256, 0, stream>>>(g, Wb, pb, (float*)d_out);
}

// Round 9
// 854.792 us; speedup vs baseline: 1.9696x; 1.9696x over previous
//
#include <hip/hip_runtime.h>
#include <hip/hip_bf16.h>

#define B_   32
#define T_   128
#define H_   700
#define E_   100
#define G3   2100
#define V_   32000
#define DY_  200
#define DZ_  500
#define KP   704          // g / Wb K-pad for projection GEMM; also h K size (88*8)
#define NBLK 88
#define JW   8            // hidden cols per block
#define FSTR 16
#define BT   4096
#define GP   2112         // G3 padded to 16

typedef __attribute__((ext_vector_type(8))) short bf16x8;
typedef __attribute__((ext_vector_type(4))) float f32x4;
typedef __attribute__((ext_vector_type(4))) unsigned u32x4;

__device__ __forceinline__ unsigned ld_flag(const unsigned* p) {
    return __hip_atomic_load(p, __ATOMIC_RELAXED, __HIP_MEMORY_SCOPE_AGENT);
}
__device__ __forceinline__ void st_flag(unsigned* p, unsigned v) {
    __hip_atomic_store(p, v, __ATOMIC_RELAXED, __HIP_MEMORY_SCOPE_AGENT);
}
// split fp32 into bf16 hi + bf16 lo (residual)
__device__ __forceinline__ void split_bf(float v, short& hi, short& lo) {
    __hip_bfloat16 h = __float2bfloat16(v);
    float r = v - __bfloat162float(h);
    __hip_bfloat16 l = __float2bfloat16(r);
    hi = *reinterpret_cast<short*>(&h);
    lo = *reinterpret_cast<short*>(&l);
}

// ---------------- proj_W [700][32000] fp32 -> Wb [32000][704] bf16 ----------------
__global__ __launch_bounds__(256)
void wconv_kernel(const float* __restrict__ W, __hip_bfloat16* __restrict__ Wb) {
    __shared__ float tile[32][33];
    const int n0 = blockIdx.x * 32, k0 = blockIdx.y * 32;
    const int tx = threadIdx.x, ty = threadIdx.y;
    #pragma unroll
    for (int i = 0; i < 4; ++i) {
        int k = k0 + ty + 8 * i;
        float v = (k < H_) ? W[(size_t)k * V_ + n0 + tx] : 0.0f;
        tile[ty + 8 * i][tx] = v;
    }
    __syncthreads();
    #pragma unroll
    for (int i = 0; i < 4; ++i) {
        int nn = ty + 8 * i;
        Wb[(size_t)(n0 + nn) * KP + k0 + tx] = __float2bfloat16(tile[tx][nn]);
    }
}

// ---------------- gk [100][2100] fp32 -> gkt hi/lo [2112][128] bf16 (transposed, padded) ----------------
__global__ __launch_bounds__(256)
void gkt_kernel(const float* __restrict__ gk,
                unsigned short* __restrict__ gkthi, unsigned short* __restrict__ gktlo) {
    __shared__ float tile[32][33];
    const int c0 = blockIdx.x * 32, k0 = blockIdx.y * 32;
    const int tx = threadIdx.x, ty = threadIdx.y;
    #pragma unroll
    for (int i = 0; i < 4; ++i) {
        int k = k0 + ty + 8 * i, c = c0 + tx;
        tile[ty + 8 * i][tx] = (k < E_ && c < G3) ? gk[(size_t)k * G3 + c] : 0.0f;
    }
    __syncthreads();
    #pragma unroll
    for (int i = 0; i < 4; ++i) {
        int cc = ty + 8 * i;
        short hi, lo; split_bf(tile[tx][cc], hi, lo);
        gkthi[(size_t)(c0 + cc) * 128 + k0 + tx] = (unsigned short)hi;
        gktlo[(size_t)(c0 + cc) * 128 + k0 + tx] = (unsigned short)lo;
    }
}

// ---------------- mask[b][t][j] -> mask_t[j][t*32+b] (bf16; mask in {0,2} exact) ----------------
__global__ __launch_bounds__(256)
void maskt_kernel(const float* __restrict__ mask, __hip_bfloat16* __restrict__ mkt) {
    __shared__ float tl[32][33];
    const int j0 = blockIdx.x * 32, t = blockIdx.y;
    const int tx = threadIdx.x, ty = threadIdx.y;
    #pragma unroll
    for (int i = 0; i < 4; ++i) {
        int b = ty + 8 * i, j = j0 + tx;
        tl[b][tx] = (j < H_) ? mask[(size_t)(b * T_ + t) * H_ + j] : 0.0f;
    }
    __syncthreads();
    #pragma unroll
    for (int i = 0; i < 4; ++i) {
        int cc = ty + 8 * i;
        if (j0 + cc < H_)
            mkt[(size_t)(j0 + cc) * BT + t * 32 + tx] = __float2bfloat16(tl[tx][cc]);
    }
}

// ---------------- xpt[c][t*32+b] = (emb-gather @ gru1_k + gb) transposed, via MFMA hi/lo ----------------
// M = c (2112, from gkt), N = tb (4096, t-major), K = 128 (E_ padded).
__global__ __launch_bounds__(256)
void xpt_gemm(const int* __restrict__ di, const float* __restrict__ emb,
              const float* __restrict__ gb,
              const unsigned short* __restrict__ gkthi, const unsigned short* __restrict__ gktlo,
              float* __restrict__ xpt) {
    __shared__ int di_l[64];
    __shared__ unsigned short Bhi[64][136], Blo[64][136];
    const int tid = threadIdx.x;
    const int c0 = blockIdx.x * 64, n0 = blockIdx.y * 64;
    const int wv = tid >> 6, lane = tid & 63, lr = lane & 15, lkg = lane >> 4;

    if (tid < 64) {
        int tb = n0 + tid;
        di_l[tid] = di[(tb & 31) * T_ + (tb >> 5)];   // [c][t*32+b] layout
    }
    __syncthreads();
    for (int e = tid; e < 64 * 128; e += 256) {
        int r = e >> 7, k = e & 127;
        float v = (k < E_) ? emb[(size_t)di_l[r] * E_ + k] : 0.0f;
        short hi, lo; split_bf(v, hi, lo);
        Bhi[r][k] = (unsigned short)hi; Blo[r][k] = (unsigned short)lo;
    }
    __syncthreads();

    bf16x8 ahi[4], alo[4];
    const int crow = c0 + wv * 16 + lr;
    #pragma unroll
    for (int kt = 0; kt < 4; ++kt) {
        ahi[kt] = *(const bf16x8*)&gkthi[(size_t)crow * 128 + kt * 32 + lkg * 8];
        alo[kt] = *(const bf16x8*)&gktlo[(size_t)crow * 128 + kt * 32 + lkg * 8];
    }
    f32x4 acc[4];
    #pragma unroll
    for (int n = 0; n < 4; ++n) acc[n] = (f32x4){0.f, 0.f, 0.f, 0.f};
    #pragma unroll
    for (int kt = 0; kt < 4; ++kt) {
        #pragma unroll
        for (int n = 0; n < 4; ++n) {
            bf16x8 bh = *(const bf16x8*)&Bhi[n * 16 + lr][kt * 32 + lkg * 8];
            bf16x8 bl = *(const bf16x8*)&Blo[n * 16 + lr][kt * 32 + lkg * 8];
            acc[n] = __builtin_amdgcn_mfma_f32_16x16x32_bf16(ahi[kt], bh, acc[n], 0, 0, 0);
            acc[n] = __builtin_amdgcn_mfma_f32_16x16x32_bf16(ahi[kt], bl, acc[n], 0, 0, 0);
            acc[n] = __builtin_amdgcn_mfma_f32_16x16x32_bf16(alo[kt], bh, acc[n], 0, 0, 0);
        }
    }
    float bv[4];
    #pragma unroll
    for (int r = 0; r < 4; ++r) {
        int cr = c0 + wv * 16 + lkg * 4 + r;
        bv[r] = (cr < G3) ? gb[cr] : 0.f;
    }
    #pragma unroll
    for (int n = 0; n < 4; ++n)
        #pragma unroll
        for (int r = 0; r < 4; ++r) {
            int cr = c0 + wv * 16 + lkg * 4 + r;
            xpt[(size_t)cr * BT + n0 + n * 16 + lr] = acc[n][r] + bv[r];
        }
}

// ---------------- persistent GRU: 88 blocks, contiguous per-block h regions ----------------
// Block owns JW=8 h-cols. h layout: hb[parity][owner(88)][plane(hi/lo)][b(32)][jl(8)] u16;
// per-owner region = 1KB contiguous -> publish = 64 x 16B stores (16 lines);
// pull: fragment for (k-tile, lkg) = ONE dwordx4 from owner (ktile*4+lkg).
__global__ __launch_bounds__(256, 1)
void gru_kernel(const float* __restrict__ labels, const float* __restrict__ zin,
                const float* __restrict__ W1, const float* __restrict__ b1,
                const float* __restrict__ xpt, const __hip_bfloat16* __restrict__ mkt,
                const float* __restrict__ rk, const float* __restrict__ gb,
                unsigned short* __restrict__ hb,
                __hip_bfloat16* __restrict__ g_out, unsigned* __restrict__ flags) {
    __shared__ float part2[4 * 2 * 16 * 33];              // [wv][m][row][2*16+pad]
    __shared__ float xbuf[24 * 32];                       // [gate*8+jl][b]
    __shared__ float mbuf[8 * 32];                        // [jl][b]
    __shared__ alignas(16) short smhi[32 * 8], smlo[32 * 8];  // [b][jl]

    const int tid = threadIdx.x;
    const int blk = blockIdx.x;
    const int j0  = blk * JW;
    const int wv = tid >> 6, lane = tid & 63, lr = lane & 15, lkg = lane >> 4;
    const int ktb = (wv < 2) ? wv * 6 : 12 + (wv - 2) * 5;   // k-tile base
    const int tn  = (wv < 2) ? 6 : 5;                        // k-tiles this wave

    // ---- rk B-frags in registers (hi/lo). n-tile col c = n*16+lr; c<24 valid ----
    bf16x8 bhi[2][6], blo[2][6];
    #pragma unroll
    for (int n = 0; n < 2; ++n)
        #pragma unroll
        for (int t = 0; t < 6; ++t) {
            bf16x8 h8, l8;
            int c = n * 16 + lr;
            int gate = c >> 3, jl = c & 7, j = j0 + jl;
            #pragma unroll
            for (int i = 0; i < 8; ++i) {
                int k = (ktb + t) * 32 + lkg * 8 + i;
                float v = (t < tn && c < 24 && j < H_ && k < H_)
                            ? rk[(size_t)k * G3 + gate * H_ + j] : 0.0f;
                short hi, lo; split_bf(v, hi, lo);
                h8[i] = hi; l8[i] = lo;
            }
            bhi[n][t] = h8; blo[n][t] = l8;
        }

    // ---- h0 + biases: 1 output per thread (b = tid&31, jl = tid>>5) ----
    const int ob = tid & 31, ojl = tid >> 5, oj = j0 + ojl;
    float hold = 0.f, bz = 0.f, brr = 0.f, bh = 0.f;
    if (oj < H_) {
        bz  = gb[G3 + oj];
        brr = gb[G3 + H_ + oj];
        bh  = gb[G3 + 2 * H_ + oj];
        hold = (oj < DY_) ? labels[ob] * W1[oj] + b1[oj] : zin[ob * DZ_ + (oj - DY_)];
    }
    {
        short hi, lo; split_bf(hold, hi, lo);
        smhi[ob * 8 + ojl] = hi; smlo[ob * 8 + ojl] = lo;
    }
    __syncthreads();
    // publish h0 (parity 0): 64 threads x 16B from LDS
    if (tid < 64) {
        int pl = tid >> 5, q = tid & 31;
        u32x4 d = ((const u32x4*)(pl ? smlo : smhi))[q];
        unsigned short* dst = hb + (size_t)blk * 512 + pl * 256 + q * 8;
        asm volatile("global_store_dwordx4 %0, %1, off sc0 sc1" :: "v"(dst), "v"(d) : "memory");
    }
    asm volatile("s_waitcnt vmcnt(0)" ::: "memory");
    __syncthreads();
    if (tid == 0) st_flag(&flags[blk * FSTR], 1u);

    union FragU { u32x4 u; bf16x8 v; };
    struct Chunk { u32x4 a0, l0, a1, l1; };   // hi/lo x rows (lr, lr+16)

    // owner region for (k-tile T, lane group lkg) = ((ktb+T)*4 + lkg) * 512 u16
#define LOADC(T, C) do {                                                          \
        const unsigned short* rb = hb + (size_t)cur * 45056                       \
                                     + (size_t)((ktb + (T)) * 4 + lkg) * 512;     \
        asm volatile("global_load_dwordx4 %0, %1, off sc0 sc1"                    \
                     : "=v"((C).a0) : "v"(rb + lr * 8) : "memory");               \
        asm volatile("global_load_dwordx4 %0, %1, off sc0 sc1"                    \
                     : "=v"((C).l0) : "v"(rb + 256 + lr * 8) : "memory");         \
        asm volatile("global_load_dwordx4 %0, %1, off sc0 sc1"                    \
                     : "=v"((C).a1) : "v"(rb + 128 + lr * 8) : "memory");         \
        asm volatile("global_load_dwordx4 %0, %1, off sc0 sc1"                    \
                     : "=v"((C).l1) : "v"(rb + 384 + lr * 8) : "memory");         \
    } while (0)
#define PROCC(T, C) do {                                                          \
        FragU fa0, fl0, fa1, fl1;                                                 \
        fa0.u = (C).a0; fl0.u = (C).l0; fa1.u = (C).a1; fl1.u = (C).l1;           \
        _Pragma("unroll")                                                         \
        for (int n = 0; n < 2; ++n) {                                             \
            acc[0][n] = __builtin_amdgcn_mfma_f32_16x16x32_bf16(fa0.v, bhi[n][T], acc[0][n], 0, 0, 0); \
            acc[0][n] = __builtin_amdgcn_mfma_f32_16x16x32_bf16(fa0.v, blo[n][T], acc[0][n], 0, 0, 0); \
            acc[0][n] = __builtin_amdgcn_mfma_f32_16x16x32_bf16(fl0.v, bhi[n][T], acc[0][n], 0, 0, 0); \
            acc[1][n] = __builtin_amdgcn_mfma_f32_16x16x32_bf16(fa1.v, bhi[n][T], acc[1][n], 0, 0, 0); \
            acc[1][n] = __builtin_amdgcn_mfma_f32_16x16x32_bf16(fa1.v, blo[n][T], acc[1][n], 0, 0, 0); \
            acc[1][n] = __builtin_amdgcn_mfma_f32_16x16x32_bf16(fl1.v, bhi[n][T], acc[1][n], 0, 0, 0); \
        }                                                                         \
    } while (0)
#define VWAIT(N) do { asm volatile("s_waitcnt vmcnt(" #N ")" ::: "memory");       \
                      __builtin_amdgcn_sched_barrier(0); } while (0)

    for (int step = 0; step < T_; ++step) {
        const int cur = step & 1, nxt = cur ^ 1;

        // phase 1: prefetch x/mask (cached loads; overlap the poll)
        #pragma unroll
        for (int it = 0; it < 3; ++it) {
            int e = tid + it * 256;                 // 768 = 24 rows x 32 b
            int row = e >> 5, b = e & 31;
            int gate = row >> 3, jl = row & 7, j = j0 + jl;
            xbuf[e] = (j < H_) ? xpt[(size_t)(gate * H_ + j) * BT + step * 32 + b] : 0.f;
        }
        mbuf[tid & 255] = (oj < H_)
            ? __bfloat162float(mkt[(size_t)oj * BT + step * 32 + ob]) : 0.f;

        // phase 2: wait for all 88 producers of h_step
        if (tid < NBLK) {
            while (ld_flag(&flags[tid * FSTR]) < (unsigned)(step + 1))
                __builtin_amdgcn_s_sleep(1);
        }
        __syncthreads();
        VWAIT(0);                                   // explicit baseline: vmcnt == 0

        // phase 3+4: counted-vmcnt 3-deep chunk pipeline
        f32x4 acc[2][2];
        #pragma unroll
        for (int m = 0; m < 2; ++m)
            #pragma unroll
            for (int n = 0; n < 2; ++n) acc[m][n] = (f32x4){0.f, 0.f, 0.f, 0.f};
        Chunk c0, c1, c2;
        LOADC(0, c0); LOADC(1, c1); LOADC(2, c2);
        VWAIT(8); PROCC(0, c0); LOADC(3, c0);
        VWAIT(8); PROCC(1, c1); LOADC(4, c1);
        VWAIT(8); PROCC(2, c2); LOADC(5, c2);
        VWAIT(8); PROCC(3, c0);
        VWAIT(4); PROCC(4, c1);
        VWAIT(0); PROCC(5, c2);

        // phase 5: per-wave partials (C layout: col=lane&15, row=lkg*4+reg)
        #pragma unroll
        for (int m = 0; m < 2; ++m)
            #pragma unroll
            for (int n = 0; n < 2; ++n)
                #pragma unroll
                for (int r = 0; r < 4; ++r)
                    part2[((wv * 2 + m) * 16 + lkg * 4 + r) * 33 + n * 16 + lr] = acc[m][n][r];
        __syncthreads();

        // phase 6: gates, 1 output per thread
        {
            int m = ob >> 4, row = ob & 15;
            float hp0 = bz, hp1 = brr, hp2 = bh;
            #pragma unroll
            for (int w = 0; w < 4; ++w) {
                int base = ((w * 2 + m) * 16 + row) * 33;
                hp0 += part2[base + ojl];            // gate0: c = jl
                hp1 += part2[base + 8 + ojl];        // gate1: c = 8+jl
                hp2 += part2[base + 16 + ojl];       // gate2: c = 16+jl
            }
            float hn = 0.f;
            if (oj < H_) {
                float xz = xbuf[(0 * 8 + ojl) * 32 + ob];
                float xr = xbuf[(1 * 8 + ojl) * 32 + ob];
                float xh = xbuf[(2 * 8 + ojl) * 32 + ob];
                float mv = mbuf[ojl * 32 + ob];
                float zg = 1.0f / (1.0f + expf(-(xz + hp0)));
                float rg = 1.0f / (1.0f + expf(-(xr + hp1)));
                float hh = tanhf(xh + rg * hp2);
                hn = zg * hold + (1.0f - zg) * hh;
                g_out[(size_t)(ob * T_ + step) * KP + oj] = __float2bfloat16(hn * mv);
            } else {
                g_out[(size_t)(ob * T_ + step) * KP + oj] = __float2bfloat16(0.f);
            }
            hold = hn;
            short hi, lo; split_bf(hn, hi, lo);
            smhi[ob * 8 + ojl] = hi; smlo[ob * 8 + ojl] = lo;
        }
        __syncthreads();
        // publish h_{step+1}: 64 x 16B contiguous stores
        if (tid < 64) {
            int pl = tid >> 5, q = tid & 31;
            u32x4 d = ((const u32x4*)(pl ? smlo : smhi))[q];
            unsigned short* dst = hb + (size_t)nxt * 45056 + (size_t)blk * 512 + pl * 256 + q * 8;
            asm volatile("global_store_dwordx4 %0, %1, off sc0 sc1" :: "v"(dst), "v"(d) : "memory");
        }
        asm volatile("s_waitcnt vmcnt(0)" ::: "memory");
        __syncthreads();
        if (tid == 0) st_flag(&flags[blk * FSTR], (unsigned)(step + 2));
    }
#undef LOADC
#undef PROCC
#undef VWAIT
}

// ---------------- projection GEMM: C[4096][32000] = g @ Wb^T + bias ----------------
__global__ __launch_bounds__(256)
void gemm_kernel(const __hip_bfloat16* __restrict__ A, const __hip_bfloat16* __restrict__ Bw,
                 const float* __restrict__ bias, float* __restrict__ C) {
    __shared__ alignas(16) unsigned short As[128][72];
    __shared__ alignas(16) unsigned short Bs[128][72];
    const int tid = threadIdx.x;
    const int bid = blockIdx.x;
    const int co = (bid & 7) * 1000 + (bid >> 3);   // bijective XCD-chunked swizzle
    const int bm = co & 31, bn = co >> 5;
    const int rowbase = bm * 128, colbase = bn * 128;
    const int lane = tid & 63, w = tid >> 6;
    const int wm = w >> 1, wn = w & 1;
    const int lr = lane & 15, lkg = lane >> 4;

    f32x4 acc[4][4];
    #pragma unroll
    for (int i = 0; i < 4; ++i)
        #pragma unroll
        for (int j = 0; j < 4; ++j) acc[i][j] = (f32x4){0.f, 0.f, 0.f, 0.f};

    const int srow = tid >> 3, skk = (tid & 7) * 8;

    for (int kt = 0; kt < 11; ++kt) {
        const int k0 = kt * 64;
        __syncthreads();
        #pragma unroll
        for (int i = 0; i < 4; ++i) {
            int r = srow + i * 32;
            *(uint4*)&As[r][skk] = *(const uint4*)&A[(size_t)(rowbase + r) * KP + k0 + skk];
            *(uint4*)&Bs[r][skk] = *(const uint4*)&Bw[(size_t)(colbase + r) * KP + k0 + skk];
        }
        __syncthreads();
        #pragma unroll
        for (int ks = 0; ks < 2; ++ks) {
            bf16x8 af[4], bf[4];
            #pragma unroll
            for (int i = 0; i < 4; ++i)
                af[i] = *(const bf16x8*)&As[wm * 64 + i * 16 + lr][ks * 32 + lkg * 8];
            #pragma unroll
            for (int j = 0; j < 4; ++j)
                bf[j] = *(const bf16x8*)&Bs[wn * 64 + j * 16 + lr][ks * 32 + lkg * 8];
            #pragma unroll
            for (int i = 0; i < 4; ++i)
                #pragma unroll
                for (int j = 0; j < 4; ++j)
                    acc[i][j] = __builtin_amdgcn_mfma_f32_16x16x32_bf16(af[i], bf[j], acc[i][j], 0, 0, 0);
        }
    }

    float bv[4];
    #pragma unroll
    for (int j = 0; j < 4; ++j) bv[j] = bias[colbase + wn * 64 + j * 16 + lr];
    #pragma unroll
    for (int i = 0; i < 4; ++i) {
        int grow0 = rowbase + wm * 64 + i * 16 + lkg * 4;
        #pragma unroll
        for (int j = 0; j < 4; ++j) {
            int gcol = colbase + wn * 64 + j * 16 + lr;
            #pragma unroll
            for (int r = 0; r < 4; ++r)
                C[(size_t)(grow0 + r) * V_ + gcol] = acc[i][j][r] + bv[j];
        }
    }
}

extern "C" void kernel_launch(void* const* d_in, const int* in_sizes, int n_in,
                              void* d_out, int out_size, void* d_ws, size_t ws_size,
                              hipStream_t stream) {
    const float* labels = (const float*)d_in[0];
    const float* z      = (const float*)d_in[1];
    const int*   di     = (const int*)d_in[2];
    const float* mask   = (const float*)d_in[3];
    const float* emb    = (const float*)d_in[4];
    const float* W1     = (const float*)d_in[5];
    const float* b1     = (const float*)d_in[6];
    const float* g1k    = (const float*)d_in[7];
    const float* g1rk   = (const float*)d_in[8];
    const float* g1b    = (const float*)d_in[9];
    const float* pW     = (const float*)d_in[10];
    const float* pb     = (const float*)d_in[11];

    // ws layout (~52 MB)
    char* ws = (char*)d_ws;
    __hip_bfloat16* g     = (__hip_bfloat16*)ws;                    //  5,767,168
    __hip_bfloat16* Wb    = (__hip_bfloat16*)(ws + 5767168);        // 45,056,000
    unsigned short* hb    = (unsigned short*)(ws + 50823168);       //    180,224 (+8KB slack)
    unsigned*       flags = (unsigned*)(ws + 51011584);             //      5,632
    unsigned short* gkthi = (unsigned short*)(ws + 51017216);       //    540,672
    unsigned short* gktlo = (unsigned short*)(ws + 51557888);       //    540,672

    // d_out scratch for GRU-phase-only data (dead before gemm writes C)
    char* ob = (char*)d_out;
    float*          xpt = (float*)ob;                               // 34,603,008
    __hip_bfloat16* mkt = (__hip_bfloat16*)(ob + 34603008);         //  5,734,400

    hipMemsetAsync(flags, 0, NBLK * FSTR * sizeof(unsigned), stream);

    wconv_kernel<<<dim3(1000, 22), dim3(32, 8), 0, stream>>>(pW, Wb);
    gkt_kernel<<<dim3(66, 4), dim3(32, 8), 0, stream>>>(g1k, gkthi, gktlo);
    maskt_kernel<<<dim3(22, 128), dim3(32, 8), 0, stream>>>(mask, mkt);
    xpt_gemm<<<dim3(33, 64), 256, 0, stream>>>(di, emb, g1b, gkthi, gktlo, xpt);

    gru_kernel<<<dim3(NBLK), 256, 0, stream>>>(labels, z, W1, b1, xpt, mkt,
                                               g1rk, g1b, hb, g, flags);

    gemm_kernel<<<dim3(8000), 256, 0, stream>>>(g, Wb, pb, (float*)d_out);
}

// Round 10
// 851.253 us; speedup vs baseline: 1.9778x; 1.0042x over previous
//
#include <hip/hip_runtime.h>
#include <hip/hip_bf16.h>

#define B_   32
#define T_   128
#define H_   700
#define E_   100
#define G3   2100
#define V_   32000
#define DY_  200
#define DZ_  500
#define KP   704          // g / Wb K-pad for projection GEMM; also h K size (88*8)
#define NBLK 88
#define JW   8            // hidden cols per block
#define FSTR 16
#define BT   4096
#define GP   2112         // G3 padded to 16

typedef __attribute__((ext_vector_type(8))) short bf16x8;
typedef __attribute__((ext_vector_type(4))) float f32x4;
typedef __attribute__((ext_vector_type(4))) unsigned u32x4;

__device__ __forceinline__ unsigned ld_flag(const unsigned* p) {
    return __hip_atomic_load(p, __ATOMIC_RELAXED, __HIP_MEMORY_SCOPE_AGENT);
}
__device__ __forceinline__ void st_flag(unsigned* p, unsigned v) {
    __hip_atomic_store(p, v, __ATOMIC_RELAXED, __HIP_MEMORY_SCOPE_AGENT);
}
// split fp32 into bf16 hi + bf16 lo (residual)
__device__ __forceinline__ void split_bf(float v, short& hi, short& lo) {
    __hip_bfloat16 h = __float2bfloat16(v);
    float r = v - __bfloat162float(h);
    __hip_bfloat16 l = __float2bfloat16(r);
    hi = *reinterpret_cast<short*>(&h);
    lo = *reinterpret_cast<short*>(&l);
}

// global -> LDS direct (16B/lane, wave-uniform LDS base + lane*16)
#define GLDS16(g, l) __builtin_amdgcn_global_load_lds(                            \
        (const __attribute__((address_space(1))) unsigned int*)(g),               \
        (__attribute__((address_space(3))) unsigned int*)(l), 16, 0, 0)

// ---------------- proj_W [700][32000] fp32 -> Wb [32000][704] bf16 ----------------
__global__ __launch_bounds__(256)
void wconv_kernel(const float* __restrict__ W, __hip_bfloat16* __restrict__ Wb) {
    __shared__ float tile[32][33];
    const int n0 = blockIdx.x * 32, k0 = blockIdx.y * 32;
    const int tx = threadIdx.x, ty = threadIdx.y;
    #pragma unroll
    for (int i = 0; i < 4; ++i) {
        int k = k0 + ty + 8 * i;
        float v = (k < H_) ? W[(size_t)k * V_ + n0 + tx] : 0.0f;
        tile[ty + 8 * i][tx] = v;
    }
    __syncthreads();
    #pragma unroll
    for (int i = 0; i < 4; ++i) {
        int nn = ty + 8 * i;
        Wb[(size_t)(n0 + nn) * KP + k0 + tx] = __float2bfloat16(tile[tx][nn]);
    }
}

// ---------------- gk [100][2100] fp32 -> gkt hi/lo [2112][128] bf16 (transposed, padded) ----------------
__global__ __launch_bounds__(256)
void gkt_kernel(const float* __restrict__ gk,
                unsigned short* __restrict__ gkthi, unsigned short* __restrict__ gktlo) {
    __shared__ float tile[32][33];
    const int c0 = blockIdx.x * 32, k0 = blockIdx.y * 32;
    const int tx = threadIdx.x, ty = threadIdx.y;
    #pragma unroll
    for (int i = 0; i < 4; ++i) {
        int k = k0 + ty + 8 * i, c = c0 + tx;
        tile[ty + 8 * i][tx] = (k < E_ && c < G3) ? gk[(size_t)k * G3 + c] : 0.0f;
    }
    __syncthreads();
    #pragma unroll
    for (int i = 0; i < 4; ++i) {
        int cc = ty + 8 * i;
        short hi, lo; split_bf(tile[tx][cc], hi, lo);
        gkthi[(size_t)(c0 + cc) * 128 + k0 + tx] = (unsigned short)hi;
        gktlo[(size_t)(c0 + cc) * 128 + k0 + tx] = (unsigned short)lo;
    }
}

// ---------------- mask[b][t][j] -> mask_t[j][t*32+b] (bf16; mask in {0,2} exact) ----------------
__global__ __launch_bounds__(256)
void maskt_kernel(const float* __restrict__ mask, __hip_bfloat16* __restrict__ mkt) {
    __shared__ float tl[32][33];
    const int j0 = blockIdx.x * 32, t = blockIdx.y;
    const int tx = threadIdx.x, ty = threadIdx.y;
    #pragma unroll
    for (int i = 0; i < 4; ++i) {
        int b = ty + 8 * i, j = j0 + tx;
        tl[b][tx] = (j < H_) ? mask[(size_t)(b * T_ + t) * H_ + j] : 0.0f;
    }
    __syncthreads();
    #pragma unroll
    for (int i = 0; i < 4; ++i) {
        int cc = ty + 8 * i;
        if (j0 + cc < H_)
            mkt[(size_t)(j0 + cc) * BT + t * 32 + tx] = __float2bfloat16(tl[tx][cc]);
    }
}

// ---------------- xpt[c][t*32+b] = (emb-gather @ gru1_k + gb) transposed, via MFMA hi/lo ----------------
__global__ __launch_bounds__(256)
void xpt_gemm(const int* __restrict__ di, const float* __restrict__ emb,
              const float* __restrict__ gb,
              const unsigned short* __restrict__ gkthi, const unsigned short* __restrict__ gktlo,
              float* __restrict__ xpt) {
    __shared__ int di_l[64];
    __shared__ unsigned short Bhi[64][136], Blo[64][136];
    const int tid = threadIdx.x;
    const int c0 = blockIdx.x * 64, n0 = blockIdx.y * 64;
    const int wv = tid >> 6, lane = tid & 63, lr = lane & 15, lkg = lane >> 4;

    if (tid < 64) {
        int tb = n0 + tid;
        di_l[tid] = di[(tb & 31) * T_ + (tb >> 5)];   // [c][t*32+b] layout
    }
    __syncthreads();
    for (int e = tid; e < 64 * 128; e += 256) {
        int r = e >> 7, k = e & 127;
        float v = (k < E_) ? emb[(size_t)di_l[r] * E_ + k] : 0.0f;
        short hi, lo; split_bf(v, hi, lo);
        Bhi[r][k] = (unsigned short)hi; Blo[r][k] = (unsigned short)lo;
    }
    __syncthreads();

    bf16x8 ahi[4], alo[4];
    const int crow = c0 + wv * 16 + lr;
    #pragma unroll
    for (int kt = 0; kt < 4; ++kt) {
        ahi[kt] = *(const bf16x8*)&gkthi[(size_t)crow * 128 + kt * 32 + lkg * 8];
        alo[kt] = *(const bf16x8*)&gktlo[(size_t)crow * 128 + kt * 32 + lkg * 8];
    }
    f32x4 acc[4];
    #pragma unroll
    for (int n = 0; n < 4; ++n) acc[n] = (f32x4){0.f, 0.f, 0.f, 0.f};
    #pragma unroll
    for (int kt = 0; kt < 4; ++kt) {
        #pragma unroll
        for (int n = 0; n < 4; ++n) {
            bf16x8 bh = *(const bf16x8*)&Bhi[n * 16 + lr][kt * 32 + lkg * 8];
            bf16x8 bl = *(const bf16x8*)&Blo[n * 16 + lr][kt * 32 + lkg * 8];
            acc[n] = __builtin_amdgcn_mfma_f32_16x16x32_bf16(ahi[kt], bh, acc[n], 0, 0, 0);
            acc[n] = __builtin_amdgcn_mfma_f32_16x16x32_bf16(ahi[kt], bl, acc[n], 0, 0, 0);
            acc[n] = __builtin_amdgcn_mfma_f32_16x16x32_bf16(alo[kt], bh, acc[n], 0, 0, 0);
        }
    }
    float bv[4];
    #pragma unroll
    for (int r = 0; r < 4; ++r) {
        int cr = c0 + wv * 16 + lkg * 4 + r;
        bv[r] = (cr < G3) ? gb[cr] : 0.f;
    }
    #pragma unroll
    for (int n = 0; n < 4; ++n)
        #pragma unroll
        for (int r = 0; r < 4; ++r) {
            int cr = c0 + wv * 16 + lkg * 4 + r;
            xpt[(size_t)cr * BT + n0 + n * 16 + lr] = acc[n][r] + bv[r];
        }
}

// ---------------- persistent GRU: 88 blocks, contiguous per-block h regions ----------------
__global__ __launch_bounds__(256, 1)
void gru_kernel(const float* __restrict__ labels, const float* __restrict__ zin,
                const float* __restrict__ W1, const float* __restrict__ b1,
                const float* __restrict__ xpt, const __hip_bfloat16* __restrict__ mkt,
                const float* __restrict__ rk, const float* __restrict__ gb,
                unsigned short* __restrict__ hb,
                __hip_bfloat16* __restrict__ g_out, unsigned* __restrict__ flags) {
    __shared__ float part2[4 * 2 * 16 * 33];              // [wv][m][row][2*16+pad]
    __shared__ float xbuf[24 * 32];                       // [gate*8+jl][b]
    __shared__ float mbuf[8 * 32];                        // [jl][b]
    __shared__ alignas(16) short smhi[32 * 8], smlo[32 * 8];  // [b][jl]

    const int tid = threadIdx.x;
    const int blk = blockIdx.x;
    const int j0  = blk * JW;
    const int wv = tid >> 6, lane = tid & 63, lr = lane & 15, lkg = lane >> 4;
    const int ktb = (wv < 2) ? wv * 6 : 12 + (wv - 2) * 5;   // k-tile base
    const int tn  = (wv < 2) ? 6 : 5;                        // k-tiles this wave

    // ---- rk B-frags in registers (hi/lo). n-tile col c = n*16+lr; c<24 valid ----
    bf16x8 bhi[2][6], blo[2][6];
    #pragma unroll
    for (int n = 0; n < 2; ++n)
        #pragma unroll
        for (int t = 0; t < 6; ++t) {
            bf16x8 h8, l8;
            int c = n * 16 + lr;
            int gate = c >> 3, jl = c & 7, j = j0 + jl;
            #pragma unroll
            for (int i = 0; i < 8; ++i) {
                int k = (ktb + t) * 32 + lkg * 8 + i;
                float v = (t < tn && c < 24 && j < H_ && k < H_)
                            ? rk[(size_t)k * G3 + gate * H_ + j] : 0.0f;
                short hi, lo; split_bf(v, hi, lo);
                h8[i] = hi; l8[i] = lo;
            }
            bhi[n][t] = h8; blo[n][t] = l8;
        }

    // ---- h0 + biases: 1 output per thread (b = tid&31, jl = tid>>5) ----
    const int ob = tid & 31, ojl = tid >> 5, oj = j0 + ojl;
    float hold = 0.f, bz = 0.f, brr = 0.f, bh = 0.f;
    if (oj < H_) {
        bz  = gb[G3 + oj];
        brr = gb[G3 + H_ + oj];
        bh  = gb[G3 + 2 * H_ + oj];
        hold = (oj < DY_) ? labels[ob] * W1[oj] + b1[oj] : zin[ob * DZ_ + (oj - DY_)];
    }
    {
        short hi, lo; split_bf(hold, hi, lo);
        smhi[ob * 8 + ojl] = hi; smlo[ob * 8 + ojl] = lo;
    }
    __syncthreads();
    // publish h0 (parity 0): 64 threads x 16B from LDS
    if (tid < 64) {
        int pl = tid >> 5, q = tid & 31;
        u32x4 d = ((const u32x4*)(pl ? smlo : smhi))[q];
        unsigned short* dst = hb + (size_t)blk * 512 + pl * 256 + q * 8;
        asm volatile("global_store_dwordx4 %0, %1, off sc0 sc1" :: "v"(dst), "v"(d) : "memory");
    }
    asm volatile("s_waitcnt vmcnt(0)" ::: "memory");
    __syncthreads();
    if (tid == 0) st_flag(&flags[blk * FSTR], 1u);

    union FragU { u32x4 u; bf16x8 v; };
    struct Chunk { u32x4 a0, l0, a1, l1; };   // hi/lo x rows (lr, lr+16)

    // owner region for (k-tile T, lane group lkg) = ((ktb+T)*4 + lkg) * 512 u16
#define LOADC(T, C) do {                                                          \
        const unsigned short* rb = hb + (size_t)cur * 45056                       \
                                     + (size_t)((ktb + (T)) * 4 + lkg) * 512;     \
        asm volatile("global_load_dwordx4 %0, %1, off sc0 sc1"                    \
                     : "=v"((C).a0) : "v"(rb + lr * 8) : "memory");               \
        asm volatile("global_load_dwordx4 %0, %1, off sc0 sc1"                    \
                     : "=v"((C).l0) : "v"(rb + 256 + lr * 8) : "memory");         \
        asm volatile("global_load_dwordx4 %0, %1, off sc0 sc1"                    \
                     : "=v"((C).a1) : "v"(rb + 128 + lr * 8) : "memory");         \
        asm volatile("global_load_dwordx4 %0, %1, off sc0 sc1"                    \
                     : "=v"((C).l1) : "v"(rb + 384 + lr * 8) : "memory");         \
    } while (0)
#define PROCC(T, C) do {                                                          \
        FragU fa0, fl0, fa1, fl1;                                                 \
        fa0.u = (C).a0; fl0.u = (C).l0; fa1.u = (C).a1; fl1.u = (C).l1;           \
        _Pragma("unroll")                                                         \
        for (int n = 0; n < 2; ++n) {                                             \
            acc[0][n] = __builtin_amdgcn_mfma_f32_16x16x32_bf16(fa0.v, bhi[n][T], acc[0][n], 0, 0, 0); \
            acc[0][n] = __builtin_amdgcn_mfma_f32_16x16x32_bf16(fa0.v, blo[n][T], acc[0][n], 0, 0, 0); \
            acc[0][n] = __builtin_amdgcn_mfma_f32_16x16x32_bf16(fl0.v, bhi[n][T], acc[0][n], 0, 0, 0); \
            acc[1][n] = __builtin_amdgcn_mfma_f32_16x16x32_bf16(fa1.v, bhi[n][T], acc[1][n], 0, 0, 0); \
            acc[1][n] = __builtin_amdgcn_mfma_f32_16x16x32_bf16(fa1.v, blo[n][T], acc[1][n], 0, 0, 0); \
            acc[1][n] = __builtin_amdgcn_mfma_f32_16x16x32_bf16(fl1.v, bhi[n][T], acc[1][n], 0, 0, 0); \
        }                                                                         \
    } while (0)
#define VWAIT(N) do { asm volatile("s_waitcnt vmcnt(" #N ")" ::: "memory");       \
                      __builtin_amdgcn_sched_barrier(0); } while (0)

    for (int step = 0; step < T_; ++step) {
        const int cur = step & 1, nxt = cur ^ 1;

        // phase 1: prefetch x/mask (cached loads; overlap the poll)
        #pragma unroll
        for (int it = 0; it < 3; ++it) {
            int e = tid + it * 256;                 // 768 = 24 rows x 32 b
            int row = e >> 5, b = e & 31;
            int gate = row >> 3, jl = row & 7, j = j0 + jl;
            xbuf[e] = (j < H_) ? xpt[(size_t)(gate * H_ + j) * BT + step * 32 + b] : 0.f;
        }
        mbuf[tid & 255] = (oj < H_)
            ? __bfloat162float(mkt[(size_t)oj * BT + step * 32 + ob]) : 0.f;

        // phase 2: wait for all 88 producers of h_step
        if (tid < NBLK) {
            while (ld_flag(&flags[tid * FSTR]) < (unsigned)(step + 1))
                __builtin_amdgcn_s_sleep(1);
        }
        __syncthreads();
        VWAIT(0);                                   // explicit baseline: vmcnt == 0

        // phase 3+4: counted-vmcnt 3-deep chunk pipeline
        f32x4 acc[2][2];
        #pragma unroll
        for (int m = 0; m < 2; ++m)
            #pragma unroll
            for (int n = 0; n < 2; ++n) acc[m][n] = (f32x4){0.f, 0.f, 0.f, 0.f};
        Chunk c0, c1, c2;
        LOADC(0, c0); LOADC(1, c1); LOADC(2, c2);
        VWAIT(8); PROCC(0, c0); LOADC(3, c0);
        VWAIT(8); PROCC(1, c1); LOADC(4, c1);
        VWAIT(8); PROCC(2, c2); LOADC(5, c2);
        VWAIT(8); PROCC(3, c0);
        VWAIT(4); PROCC(4, c1);
        VWAIT(0); PROCC(5, c2);

        // phase 5: per-wave partials (C layout: col=lane&15, row=lkg*4+reg)
        #pragma unroll
        for (int m = 0; m < 2; ++m)
            #pragma unroll
            for (int n = 0; n < 2; ++n)
                #pragma unroll
                for (int r = 0; r < 4; ++r)
                    part2[((wv * 2 + m) * 16 + lkg * 4 + r) * 33 + n * 16 + lr] = acc[m][n][r];
        __syncthreads();

        // phase 6: gates, 1 output per thread
        {
            int m = ob >> 4, row = ob & 15;
            float hp0 = bz, hp1 = brr, hp2 = bh;
            #pragma unroll
            for (int w = 0; w < 4; ++w) {
                int base = ((w * 2 + m) * 16 + row) * 33;
                hp0 += part2[base + ojl];            // gate0: c = jl
                hp1 += part2[base + 8 + ojl];        // gate1: c = 8+jl
                hp2 += part2[base + 16 + ojl];       // gate2: c = 16+jl
            }
            float hn = 0.f;
            if (oj < H_) {
                float xz = xbuf[(0 * 8 + ojl) * 32 + ob];
                float xr = xbuf[(1 * 8 + ojl) * 32 + ob];
                float xh = xbuf[(2 * 8 + ojl) * 32 + ob];
                float mv = mbuf[ojl * 32 + ob];
                float zg = 1.0f / (1.0f + expf(-(xz + hp0)));
                float rg = 1.0f / (1.0f + expf(-(xr + hp1)));
                float hh = tanhf(xh + rg * hp2);
                hn = zg * hold + (1.0f - zg) * hh;
                g_out[(size_t)(ob * T_ + step) * KP + oj] = __float2bfloat16(hn * mv);
            } else {
                g_out[(size_t)(ob * T_ + step) * KP + oj] = __float2bfloat16(0.f);
            }
            hold = hn;
            short hi, lo; split_bf(hn, hi, lo);
            smhi[ob * 8 + ojl] = hi; smlo[ob * 8 + ojl] = lo;
        }
        __syncthreads();
        // publish h_{step+1}: 64 x 16B contiguous stores
        if (tid < 64) {
            int pl = tid >> 5, q = tid & 31;
            u32x4 d = ((const u32x4*)(pl ? smlo : smhi))[q];
            unsigned short* dst = hb + (size_t)nxt * 45056 + (size_t)blk * 512 + pl * 256 + q * 8;
            asm volatile("global_store_dwordx4 %0, %1, off sc0 sc1" :: "v"(dst), "v"(d) : "memory");
        }
        asm volatile("s_waitcnt vmcnt(0)" ::: "memory");
        __syncthreads();
        if (tid == 0) st_flag(&flags[blk * FSTR], (unsigned)(step + 2));
    }
#undef LOADC
#undef PROCC
#undef VWAIT
}

// ---------------- projection GEMM: C[4096][32000] = g @ Wb^T + bias ----------------
// m97 structure: linear [128][64] LDS tiles staged via global_load_lds width=16.
__global__ __launch_bounds__(256)
void gemm_kernel(const __hip_bfloat16* __restrict__ A, const __hip_bfloat16* __restrict__ Bw,
                 const float* __restrict__ bias, float* __restrict__ C) {
    __shared__ alignas(16) unsigned short As[128 * 64];
    __shared__ alignas(16) unsigned short Bs[128 * 64];
    const int tid = threadIdx.x;
    const int bid = blockIdx.x;
    const int co = (bid & 7) * 1000 + (bid >> 3);   // bijective XCD-chunked swizzle
    const int bm = co & 31, bn = co >> 5;
    const int rowbase = bm * 128, colbase = bn * 128;
    const int lane = tid & 63, w = tid >> 6;
    const int wm = w >> 1, wn = w & 1;
    const int lr = lane & 15, lkg = lane >> 4;
    const int srl = lane >> 3;          // staging: row within 8-row group
    const int scol = (lane & 7) * 8;    // staging: col offset (bf16)

    f32x4 acc[4][4];
    #pragma unroll
    for (int i = 0; i < 4; ++i)
        #pragma unroll
        for (int j = 0; j < 4; ++j) acc[i][j] = (f32x4){0.f, 0.f, 0.f, 0.f};

    for (int kt = 0; kt < 11; ++kt) {
        const int k0 = kt * 64;
        __syncthreads();
        #pragma unroll
        for (int i = 0; i < 4; ++i) {
            const int r0 = w * 32 + i * 8;          // wave-uniform
            GLDS16(&A [(size_t)(rowbase + r0 + srl) * KP + k0 + scol], &As[r0 * 64]);
            GLDS16(&Bw[(size_t)(colbase + r0 + srl) * KP + k0 + scol], &Bs[r0 * 64]);
        }
        __syncthreads();
        #pragma unroll
        for (int ks = 0; ks < 2; ++ks) {
            bf16x8 af[4], bf[4];
            #pragma unroll
            for (int i = 0; i < 4; ++i)
                af[i] = *(const bf16x8*)&As[(wm * 64 + i * 16 + lr) * 64 + ks * 32 + lkg * 8];
            #pragma unroll
            for (int j = 0; j < 4; ++j)
                bf[j] = *(const bf16x8*)&Bs[(wn * 64 + j * 16 + lr) * 64 + ks * 32 + lkg * 8];
            #pragma unroll
            for (int i = 0; i < 4; ++i)
                #pragma unroll
                for (int j = 0; j < 4; ++j)
                    acc[i][j] = __builtin_amdgcn_mfma_f32_16x16x32_bf16(af[i], bf[j], acc[i][j], 0, 0, 0);
        }
    }

    float bv[4];
    #pragma unroll
    for (int j = 0; j < 4; ++j) bv[j] = bias[colbase + wn * 64 + j * 16 + lr];
    #pragma unroll
    for (int i = 0; i < 4; ++i) {
        int grow0 = rowbase + wm * 64 + i * 16 + lkg * 4;
        #pragma unroll
        for (int j = 0; j < 4; ++j) {
            int gcol = colbase + wn * 64 + j * 16 + lr;
            #pragma unroll
            for (int r = 0; r < 4; ++r)
                C[(size_t)(grow0 + r) * V_ + gcol] = acc[i][j][r] + bv[j];
        }
    }
}

extern "C" void kernel_launch(void* const* d_in, const int* in_sizes, int n_in,
                              void* d_out, int out_size, void* d_ws, size_t ws_size,
                              hipStream_t stream) {
    const float* labels = (const float*)d_in[0];
    const float* z      = (const float*)d_in[1];
    const int*   di     = (const int*)d_in[2];
    const float* mask   = (const float*)d_in[3];
    const float* emb    = (const float*)d_in[4];
    const float* W1     = (const float*)d_in[5];
    const float* b1     = (const float*)d_in[6];
    const float* g1k    = (const float*)d_in[7];
    const float* g1rk   = (const float*)d_in[8];
    const float* g1b    = (const float*)d_in[9];
    const float* pW     = (const float*)d_in[10];
    const float* pb     = (const float*)d_in[11];

    // ws layout (~52 MB)
    char* ws = (char*)d_ws;
    __hip_bfloat16* g     = (__hip_bfloat16*)ws;                    //  5,767,168
    __hip_bfloat16* Wb    = (__hip_bfloat16*)(ws + 5767168);        // 45,056,000
    unsigned short* hb    = (unsigned short*)(ws + 50823168);       //    180,224 (+8KB slack)
    unsigned*       flags = (unsigned*)(ws + 51011584);             //      5,632
    unsigned short* gkthi = (unsigned short*)(ws + 51017216);       //    540,672
    unsigned short* gktlo = (unsigned short*)(ws + 51557888);       //    540,672

    // d_out scratch for GRU-phase-only data (dead before gemm writes C)
    char* ob = (char*)d_out;
    float*          xpt = (float*)ob;                               // 34,603,008
    __hip_bfloat16* mkt = (__hip_bfloat16*)(ob + 34603008);         //  5,734,400

    hipMemsetAsync(flags, 0, NBLK * FSTR * sizeof(unsigned), stream);

    wconv_kernel<<<dim3(1000, 22), dim3(32, 8), 0, stream>>>(pW, Wb);
    gkt_kernel<<<dim3(66, 4), dim3(32, 8), 0, stream>>>(g1k, gkthi, gktlo);
    maskt_kernel<<<dim3(22, 128), dim3(32, 8), 0, stream>>>(mask, mkt);
    xpt_gemm<<<dim3(33, 64), 256, 0, stream>>>(di, emb, g1b, gkthi, gktlo, xpt);

    gru_kernel<<<dim3(NBLK), 256, 0, stream>>>(labels, z, W1, b1, xpt, mkt,
                                               g1rk, g1b, hb, g, flags);

    gemm_kernel<<<dim3(8000), 256, 0, stream>>>(g, Wb, pb, (float*)d_out);
}